// Round 4
// baseline (538.461 us; speedup 1.0000x reference)
//
#include <hip/hip_runtime.h>

// SVDAdapter: out = x @ (W + U*s*V^T)^T
// x: (8192,4096) f32, W: (4096,4096) f32, U: (4096,16), s: (16), V: (4096,16)
// Fast path:
//   prep (1 dispatch): x -> xh f16 (16B stores)  ||  wh = f16(W + (U s) V^T)
//   gemm: 256^2 tile, BK=64, 8 waves, 32x32x16 f16 MFMA, 4 phases/K-tile,
//     ONE barrier per phase, counted lgkmcnt(6) fragment pipeline, counted
//     vmcnt(6) residency (twice per tile), staging rotation:
//       P1: A_k1(t+1)  P2: B_k1(t+1)  P3: A_k0(t+2)  P4: B_k0(t+2)
//     WAR ledger: every region has a completing lgkm-wait + barrier between
//     last read-issue and overwrite. Last two tiles peeled (vmcnt(4)/(0)).
//   Frag layouts: A/B row=lane&31, k=8*(lane>>5)+e (analog of verified
//   16x16x32); C/D col=lane&31, row=(reg&3)+8*(reg>>2)+4*(lane>>5) [m74/m101].
// Fallback (ws too small): fp32 VALU GEMM + rank-16 fixup (unchanged).

#define IN_F   4096
#define OUT_F  4096
#define RANK   16
#define M_ROWS 8192
#define BM 256
#define BN 256
#define BK 64
#define NT (IN_F / BK)   // 64 K-tiles

typedef _Float16 f16x8 __attribute__((ext_vector_type(8)));
typedef _Float16 f16x4 __attribute__((ext_vector_type(4)));
typedef float    f32x4 __attribute__((ext_vector_type(4)));
typedef float    f32x16 __attribute__((ext_vector_type(16)));

// ---------------------------------------------------------------- async copy
__device__ __forceinline__ void async16(const void* gp, void* lp) {
  __builtin_amdgcn_global_load_lds(
      (const __attribute__((address_space(1))) void*)gp,
      (__attribute__((address_space(3))) void*)lp, 16, 0, 0);
}

// ---------------------------------------------------------------- fused prep
// blocks [0, 4096):   x (f32) -> xh (f16), grid-stride, 16B stores
// blocks [4096, 6144): wh[o][i] = f16( W[o][i] + sum_r U[o][r]*s[r]*V[i][r] )
#define SPLIT_BLOCKS 4096

__global__ __launch_bounds__(256)
void prep_kernel(const float* __restrict__ x, _Float16* __restrict__ xh,
                 const float* __restrict__ W, const float* __restrict__ U,
                 const float* __restrict__ S, const float* __restrict__ V,
                 _Float16* __restrict__ wh) {
  if (blockIdx.x < SPLIT_BLOCKS) {
    // group = 8 floats -> one f16x8 (16B) store
    size_t t = (size_t)blockIdx.x * 256 + threadIdx.x;
    const float4* xin = (const float4*)x;
#pragma unroll
    for (int it = 0; it < 4; ++it) {  // 8192*4096/8 groups / (4096*256)
      float4 a = xin[2 * t];
      float4 b = xin[2 * t + 1];
      f16x8 h;
      h[0] = (_Float16)a.x; h[1] = (_Float16)a.y;
      h[2] = (_Float16)a.z; h[3] = (_Float16)a.w;
      h[4] = (_Float16)b.x; h[5] = (_Float16)b.y;
      h[6] = (_Float16)b.z; h[7] = (_Float16)b.w;
      ((f16x8*)xh)[t] = h;
      t += (size_t)SPLIT_BLOCKS * 256;
    }
  } else {
    int t = (int)(blockIdx.x - SPLIT_BLOCKS) * 256 + threadIdx.x;  // < 1024*512
    int i4 = (t & 1023) << 2;                 // i column group
    int o0 = (t >> 10) << 3;                  // 8 o-rows per thread

    float v[4][RANK];
#pragma unroll
    for (int j = 0; j < 4; ++j) {
      const float4* vp = (const float4*)(V + (size_t)(i4 + j) * RANK);
#pragma unroll
      for (int q = 0; q < 4; ++q) {
        float4 vv = vp[q];
        v[j][q * 4 + 0] = vv.x; v[j][q * 4 + 1] = vv.y;
        v[j][q * 4 + 2] = vv.z; v[j][q * 4 + 3] = vv.w;
      }
    }
    float sv[RANK];
#pragma unroll
    for (int r = 0; r < RANK; r += 4) {
      float4 ss = *(const float4*)(S + r);
      sv[r] = ss.x; sv[r + 1] = ss.y; sv[r + 2] = ss.z; sv[r + 3] = ss.w;
    }

    for (int oo = 0; oo < 8; ++oo) {
      int o = o0 + oo;
      float us[RANK];
      const float4* up = (const float4*)(U + (size_t)o * RANK);
#pragma unroll
      for (int r = 0; r < RANK; r += 4) {
        float4 uu = up[r >> 2];
        us[r] = uu.x * sv[r]; us[r + 1] = uu.y * sv[r + 1];
        us[r + 2] = uu.z * sv[r + 2]; us[r + 3] = uu.w * sv[r + 3];
      }
      float4 w = *(const float4*)(W + (size_t)o * IN_F + i4);
      float d0 = w.x, d1 = w.y, d2 = w.z, d3 = w.w;
#pragma unroll
      for (int r = 0; r < RANK; ++r) {
        d0 += us[r] * v[0][r];
        d1 += us[r] * v[1][r];
        d2 += us[r] * v[2][r];
        d3 += us[r] * v[3][r];
      }
      f16x4 h;
      h[0] = (_Float16)d0; h[1] = (_Float16)d1;
      h[2] = (_Float16)d2; h[3] = (_Float16)d3;
      *(f16x4*)(wh + (size_t)o * IN_F + i4) = h;
    }
  }
}

// ---------------------------------------------------------------- GEMM (fast)
// out[m][o] = sum_k xh[m][k]*wh[o][k]  ("NT": both operands K-major)
// LDS: 8 regions of 16 KiB (256 rows x 64B):
//   buf p @ p*65536:  A_k0 +0, B_k0 +16384, A_k1 +32768, B_k1 +49152
// Rows = 4 chunks of 16B; stored chunk c holds data chunk c ^ ((r>>1)&3)
// (swizzle applied on the GLOBAL gather; LDS dest stays linear).
//
// Per K-tile: 4 k-steps s=0..3 (16 K each); region k0 holds s=0,1; k1 s=2,3.
// Phase p computes k-step p-1's MFMAs while reading k-step p's fragments:
//   P1: bar; rd set1<-s1(k0); STG A_k1(t+1);            lgkm(6); MFMA set0
//   P2: vm(6); bar; rd set0<-s2(k1); STG B_k1(t+1);     lgkm(6); MFMA set1
//   P3: bar; rd set1<-s3(k1); STG A_k0(t+2);            lgkm(6); MFMA set0
//   P4: vm(6); bar; rd set0<-s0(t+1,k0); STG B_k0(t+2); lgkm(6); MFMA set1
__global__ __launch_bounds__(512, 2)
void gemm_kernel(const _Float16* __restrict__ xh,
                 const _Float16* __restrict__ wh,
                 float* __restrict__ out) {
  __shared__ unsigned char lds[131072];

  // bijective XCD swizzle (512 blocks % 8 == 0)
  const int orig = blockIdx.x;
  const int wg = (orig & 7) * 64 + (orig >> 3);
  const int mt = wg >> 4;          // 0..31
  const int nt = wg & 15;          // 0..15 fastest -> neighbors share A panel
  const int blockM = mt * BM;
  const int blockN = nt * BN;

  const int tid = threadIdx.x;
  const int lane = tid & 63;
  const int wave = tid >> 6;       // 0..7
  const int wm = wave >> 2;        // 0..1  -> 128-row half
  const int wn = wave & 3;         // 0..3  -> 64-col quarter

  // ---- staging addresses: one half-tile = 256 rows x 32 f16 = 1024 chunks,
  //      512 threads x 2 slots; LDS dest linear in slot.
  const _Float16* aSrc[2];
  const _Float16* bSrc[2];
  unsigned ldsOff[2];
#pragma unroll
  for (int q = 0; q < 2; ++q) {
    int slot = q * 512 + tid;           // 0..1023
    int r = slot >> 2;                  // region row 0..255
    int c = slot & 3;                   // stored chunk
    int cd = c ^ ((r >> 1) & 3);        // data chunk (swizzle on the gather)
    aSrc[q] = xh + (size_t)(blockM + r) * IN_F + cd * 8;
    bSrc[q] = wh + (size_t)(blockN + r) * IN_F + cd * 8;
    ldsOff[q] = (unsigned)slot * 16;
  }

  // ---- 32x32x16 fragment offsets (within a k-half region), per sl=s&1.
  // lane holds row = lane&31, k = 8*(lane>>5)+e; data chunk = sl*2+kg.
  const int kg = lane >> 5;
  const int lr = lane & 31;
  unsigned offA32[4][2], offB32[2][2];
#pragma unroll
  for (int rt = 0; rt < 4; ++rt) {
    int ar = wm * 128 + rt * 32 + lr;
    int sw = (ar >> 1) & 3;
    offA32[rt][0] = (unsigned)(ar * 64 + (((0 * 2 + kg) ^ sw) * 16));
    offA32[rt][1] = (unsigned)(ar * 64 + (((1 * 2 + kg) ^ sw) * 16));
  }
#pragma unroll
  for (int ct = 0; ct < 2; ++ct) {
    int br = wn * 64 + ct * 32 + lr;
    int sw = (br >> 1) & 3;
    offB32[ct][0] = (unsigned)(br * 64 + (((0 * 2 + kg) ^ sw) * 16));
    offB32[ct][1] = (unsigned)(br * 64 + (((1 * 2 + kg) ^ sw) * 16));
  }

  f32x16 acc[4][2];
#pragma unroll
  for (int i = 0; i < 4; ++i)
#pragma unroll
    for (int j = 0; j < 2; ++j) acc[i][j] = (f32x16)(0.f);

  f16x8 a0[4], b0[2], a1[4], b1[2];

#define STG(SRC, LDSBASE, KOFS)                                      \
  {                                                                  \
    async16(SRC[0] + (KOFS), lds + (LDSBASE) + ldsOff[0]);           \
    async16(SRC[1] + (KOFS), lds + (LDSBASE) + ldsOff[1]);           \
  }
#define RD6(AA, BB, RA, RB, SL)                                      \
  {                                                                  \
    AA[0] = *(const f16x8*)(lds + (RA) + offA32[0][SL]);             \
    AA[1] = *(const f16x8*)(lds + (RA) + offA32[1][SL]);             \
    AA[2] = *(const f16x8*)(lds + (RA) + offA32[2][SL]);             \
    AA[3] = *(const f16x8*)(lds + (RA) + offA32[3][SL]);             \
    BB[0] = *(const f16x8*)(lds + (RB) + offB32[0][SL]);             \
    BB[1] = *(const f16x8*)(lds + (RB) + offB32[1][SL]);             \
  }
#define PH_BAR() asm volatile("s_barrier" ::: "memory")
#define WAITL(N) asm volatile("s_waitcnt lgkmcnt(" #N ")" ::: "memory")
#define WAITV(N) asm volatile("s_waitcnt vmcnt(" #N ")" ::: "memory")
#define MFMA8(AA, BB)                                                \
  {                                                                  \
    __builtin_amdgcn_sched_barrier(0);                               \
    __builtin_amdgcn_s_setprio(1);                                   \
    _Pragma("unroll")                                                \
    for (int rt_ = 0; rt_ < 4; ++rt_) {                              \
      _Pragma("unroll")                                              \
      for (int ct_ = 0; ct_ < 2; ++ct_)                              \
        acc[rt_][ct_] = __builtin_amdgcn_mfma_f32_32x32x16_f16(      \
            (AA)[rt_], (BB)[ct_], acc[rt_][ct_], 0, 0, 0);           \
    }                                                                \
    __builtin_amdgcn_s_setprio(0);                                   \
  }

  // ---- prologue: issue order mimics steady state (2 VMEM ops per STG):
  STG(aSrc, 0, 0);                 // A_k0(0)   [plays t-2.P3]
  STG(bSrc, 16384, 0);             // B_k0(0)   [plays t-2.P4]
  STG(aSrc, 32768, 32);            // A_k1(0)   [plays t-1.P1]
  STG(bSrc, 49152, 32);            // B_k1(0)   [plays t-1.P2]
  STG(aSrc, 65536 + 0, 64);        // A_k0(1)   [plays t-1.P3]
  STG(bSrc, 65536 + 16384, 64);    // B_k0(1)   [plays t-1.P4]
  WAITV(8);                        // A_k0(0), B_k0(0) resident
  PH_BAR();
  RD6(a0, b0, 0, 16384, 0);        // s=0 of tile 0   [plays t-1.P4's reads]

  // ---- main loop: t = 0 .. NT-3
#pragma unroll 2
  for (int t = 0; t < NT - 2; ++t) {
    const unsigned base  = (unsigned)(t & 1) << 16;
    const unsigned baseN = base ^ 65536u;
    const int kof1 = (t + 1) * BK;
    const int kof2 = (t + 2) * BK;

    // P1: compute s0, read s1 (k0 regions)
    PH_BAR();
    RD6(a1, b1, base + 0, base + 16384, 1);
    STG(aSrc, baseN + 32768, kof1 + 32);    // A_k1(t+1)
    WAITL(6);
    MFMA8(a0, b0);

    // P2: compute s1, read s2 (k1 regions; staged t-1.P1/P2 -> guard vm(6))
    WAITV(6);
    PH_BAR();
    RD6(a0, b0, base + 32768, base + 49152, 0);
    STG(bSrc, baseN + 49152, kof1 + 32);    // B_k1(t+1)
    WAITL(6);
    MFMA8(a1, b1);

    // P3: compute s2, read s3 (k1 regions)
    PH_BAR();
    RD6(a1, b1, base + 32768, base + 49152, 1);
    STG(aSrc, base + 0, kof2);              // A_k0(t+2)
    WAITL(6);
    MFMA8(a0, b0);

    // P4: compute s3, read next tile's s0 (staged t-1.P3/P4 -> guard vm(6))
    WAITV(6);
    PH_BAR();
    RD6(a0, b0, baseN + 0, baseN + 16384, 0);
    STG(bSrc, base + 16384, kof2);          // B_k0(t+2)
    WAITL(6);
    MFMA8(a1, b1);
  }

  // ---- peeled tile NT-2 (base=0, baseN=65536)
  {
    const unsigned base = 0, baseN = 65536u;
    const int kof1 = (NT - 1) * BK;

    PH_BAR();
    RD6(a1, b1, base + 0, base + 16384, 1);
    STG(aSrc, baseN + 32768, kof1 + 32);    // A_k1(NT-1)
    WAITL(6);
    MFMA8(a0, b0);

    WAITV(6);
    PH_BAR();
    RD6(a0, b0, base + 32768, base + 49152, 0);
    STG(bSrc, baseN + 49152, kof1 + 32);    // B_k1(NT-1)
    WAITL(6);
    MFMA8(a1, b1);

    PH_BAR();
    RD6(a1, b1, base + 32768, base + 49152, 1);
    WAITL(6);
    MFMA8(a0, b0);

    WAITV(4);                               // A_k0/B_k0(NT-1) resident
    PH_BAR();
    RD6(a0, b0, baseN + 0, baseN + 16384, 0);
    WAITL(6);
    MFMA8(a1, b1);
  }
  // ---- peeled tile NT-1 (base=65536): no staging
  {
    const unsigned base = 65536u;

    PH_BAR();
    RD6(a1, b1, base + 0, base + 16384, 1);
    WAITL(6);
    MFMA8(a0, b0);

    WAITV(0);                               // A_k1/B_k1(NT-1) resident
    PH_BAR();
    RD6(a0, b0, base + 32768, base + 49152, 0);
    WAITL(6);
    MFMA8(a1, b1);

    PH_BAR();
    RD6(a1, b1, base + 32768, base + 49152, 1);
    WAITL(6);
    MFMA8(a0, b0);

    PH_BAR();
    WAITL(0);
    MFMA8(a1, b1);
  }
#undef STG
#undef RD6
#undef PH_BAR
#undef WAITL
#undef WAITV
#undef MFMA8

  // C/D layout (32x32): col=lane&31, row=(reg&3)+8*(reg>>2)+4*(lane>>5)
  const int colB = blockN + wn * 64 + lr;
  const int rowB = blockM + wm * 128 + 4 * kg;
#pragma unroll
  for (int rt = 0; rt < 4; ++rt)
#pragma unroll
    for (int ct = 0; ct < 2; ++ct) {
#pragma unroll
      for (int g = 0; g < 4; ++g)
#pragma unroll
        for (int q = 0; q < 4; ++q)
          out[(size_t)(rowB + rt * 32 + 8 * g + q) * OUT_F + colB + ct * 32] =
              acc[rt][ct][g * 4 + q];
    }
}

// ================================================================ FALLBACK
// fp32 VALU GEMM out = x @ W^T (64x64 tile), then out += (x V s) U^T.
__global__ __launch_bounds__(256)
void fb_gemm(const float* __restrict__ x, const float* __restrict__ W,
             float* __restrict__ out) {
  __shared__ float xs[64][17];
  __shared__ float wsm[64][17];
  const int mt = blockIdx.x >> 6;
  const int ntile = blockIdx.x & 63;
  const int bM = mt * 64, bN = ntile * 64;
  const int t = threadIdx.x;
  const int lr = t >> 2, lc = (t & 3) * 4;
  const int tm = t >> 4, tn = t & 15;

  float acc[4][4];
#pragma unroll
  for (int i = 0; i < 4; ++i)
#pragma unroll
    for (int j = 0; j < 4; ++j) acc[i][j] = 0.f;

  for (int kk = 0; kk < IN_F; kk += 16) {
    float4 xa = *(const float4*)(x + (size_t)(bM + lr) * IN_F + kk + lc);
    float4 wa = *(const float4*)(W + (size_t)(bN + lr) * IN_F + kk + lc);
    xs[lr][lc + 0] = xa.x; xs[lr][lc + 1] = xa.y;
    xs[lr][lc + 2] = xa.z; xs[lr][lc + 3] = xa.w;
    wsm[lr][lc + 0] = wa.x; wsm[lr][lc + 1] = wa.y;
    wsm[lr][lc + 2] = wa.z; wsm[lr][lc + 3] = wa.w;
    __syncthreads();
#pragma unroll
    for (int k = 0; k < 16; ++k) {
      float a[4], b[4];
#pragma unroll
      for (int i = 0; i < 4; ++i) a[i] = xs[tm * 4 + i][k];
#pragma unroll
      for (int j = 0; j < 4; ++j) b[j] = wsm[tn * 4 + j][k];
#pragma unroll
      for (int i = 0; i < 4; ++i)
#pragma unroll
        for (int j = 0; j < 4; ++j) acc[i][j] += a[i] * b[j];
    }
    __syncthreads();
  }
#pragma unroll
  for (int i = 0; i < 4; ++i)
#pragma unroll
    for (int j = 0; j < 4; ++j)
      out[(size_t)(bM + tm * 4 + i) * OUT_F + bN + tn * 4 + j] = acc[i][j];
}

__global__ void fb_xv(const float* __restrict__ x, const float* __restrict__ V,
                      const float* __restrict__ S, float* __restrict__ xv) {
  int m = blockIdx.x * 4 + (threadIdx.x >> 6);
  int lane = threadIdx.x & 63;
  float a[RANK];
#pragma unroll
  for (int r = 0; r < RANK; ++r) a[r] = 0.f;
  for (int k = lane; k < IN_F; k += 64) {
    float xe = x[(size_t)m * IN_F + k];
    const float4* vp = (const float4*)(V + (size_t)k * RANK);
#pragma unroll
    for (int q = 0; q < 4; ++q) {
      float4 vv = vp[q];
      a[q * 4 + 0] += xe * vv.x; a[q * 4 + 1] += xe * vv.y;
      a[q * 4 + 2] += xe * vv.z; a[q * 4 + 3] += xe * vv.w;
    }
  }
#pragma unroll
  for (int r = 0; r < RANK; ++r)
    for (int off = 32; off; off >>= 1) a[r] += __shfl_down(a[r], off);
  if (lane == 0) {
#pragma unroll
    for (int r = 0; r < RANK; ++r) xv[(size_t)m * RANK + r] = a[r] * S[r];
  }
}

__global__ void fb_add(const float* __restrict__ xv, const float* __restrict__ U,
                       float* __restrict__ out) {
  size_t t = (size_t)blockIdx.x * 256 + threadIdx.x;
  int m = (int)(t >> 12), o = (int)(t & 4095);
  const float* xr = xv + (size_t)m * RANK;
  const float* ur = U + (size_t)o * RANK;
  float d = 0.f;
#pragma unroll
  for (int r = 0; r < RANK; ++r) d += xr[r] * ur[r];
  out[t] += d;
}

// ---------------------------------------------------------------- launch
extern "C" void kernel_launch(void* const* d_in, const int* in_sizes, int n_in,
                              void* d_out, int out_size, void* d_ws, size_t ws_size,
                              hipStream_t stream) {
  const float* x = (const float*)d_in[0];
  const float* W = (const float*)d_in[1];
  const float* U = (const float*)d_in[2];
  const float* s = (const float*)d_in[3];
  const float* V = (const float*)d_in[4];
  float* out = (float*)d_out;

  // workspace: xh (8192*4096 f16) + wh (4096*4096 f16) = 100 MiB
  const size_t need = ((size_t)M_ROWS * IN_F + (size_t)OUT_F * IN_F) * 2;
  if (ws_size >= need) {
    _Float16* xh = (_Float16*)d_ws;
    _Float16* wh = xh + (size_t)M_ROWS * IN_F;
    prep_kernel<<<SPLIT_BLOCKS + ((IN_F / 4) * (OUT_F / 8)) / 256, 256, 0, stream>>>(
        x, xh, W, U, s, V, wh);
    gemm_kernel<<<(M_ROWS / BM) * (OUT_F / BN), 512, 0, stream>>>(xh, wh, out);
  } else {
    float* xv = (float*)d_ws;  // 8192*16 f32 = 512 KiB
    fb_gemm<<<(M_ROWS / 64) * (OUT_F / 64), 256, 0, stream>>>(x, W, out);
    fb_xv<<<M_ROWS / 4, 256, 0, stream>>>(x, V, s, xv);
    fb_add<<<(size_t)M_ROWS * OUT_F / 256, 256, 0, stream>>>(xv, U, out);
  }
}